// Round 1
// 410.613 us; speedup vs baseline: 1.0241x; 1.0241x over previous
//
#include <hip/hip_runtime.h>

// out[b,t,d] = x[b,t,d] + pe[t,d]
// pe[t,d] = (d even) ? sin(t * 10000^(-2d/1024)) : cos(t * 10000^(-2d/1024))
//
// R3 structure: ONE fused workspace-free kernel.
//   - pe computed in-register with hardware trig in REVOLUTIONS:
//       w   = exp2(-d*C - log2(2pi))          // = 10000^(-2d/1024) / (2pi)
//       rev = t*w ; e = fma(t,w,-rev)         // e recovers the mul rounding
//       f   = fract(fract(rev) + e)           // exact mod-1, fp32 precision
//       pe  = v_sin_f32(f)  (even d)  /  v_cos_f32(f)  (odd d)
//     fract() of a slightly-negative f wraps to 1-eps, which is the correct
//     mod-1 value, so the compensation needs no branch.
//   - No pe table: the 8 MiB table didn't fit a 4 MiB per-XCD L2, so the old
//     stream kernel pulled 268 MB/pass of pe from L3. Gone.
//   - No d_ws: avoids the 1 GiB fillBufferAligned workspace re-poison that
//     dominated the rocprof top-5 (164 us @ 6.5 TB/s each).
//   - Compute budget: ~36 VALU + 12 trans ops/thread vs ~400 instr/thread
//     headroom at full HBM rate -> stays memory-bound.
//
// Mandatory traffic: 256 MiB read + 256 MiB write -> ~85 us at 6.3 TB/s.

constexpr int D_MODEL = 1024;
constexpr int T_STEPS = 2048;
constexpr int BATCH   = 32;
constexpr int TD4     = T_STEPS * D_MODEL / 4;        // float4s per [T,D] plane
constexpr int TOTAL4  = BATCH * TD4;                  // 16777216 float4s

__device__ __forceinline__ float pe_rev(float pos, float w) {
    // fraction of (pos*w) mod 1, with fma error compensation
    float p = pos * w;
    float e = fmaf(pos, w, -p);                       // exact rounding error of p
    float f = __builtin_amdgcn_fractf(p) + e;
    return __builtin_amdgcn_fractf(f);                // wrap e-induced under/overflow
}

__global__ __launch_bounds__(256) void pe_add_fused_kernel(const float* __restrict__ x,
                                                           float* __restrict__ out) {
    const int idx = blockIdx.x * blockDim.x + threadIdx.x;   // 0 .. TOTAL4-1
    const int d4  = idx & (D_MODEL / 4 - 1);                 // bits 0..7
    const int t   = (idx >> 8) & (T_STEPS - 1);              // bits 8..18
    const int d0  = d4 * 4;                                  // even

    const float C    = 0.025952563241307517f;   // 2*log2(10000)/1024
    const float L2PI = 2.6514961294723187f;     // log2(2*pi)
    const float pos  = (float)t;

    // w_j = 10000^(-2(d0+j)/1024) / (2*pi)   (exp2 on the trans pipe, cheap)
    const float w0 = __builtin_exp2f(fmaf(-(float)(d0 + 0), C, -L2PI));
    const float w1 = __builtin_exp2f(fmaf(-(float)(d0 + 1), C, -L2PI));
    const float w2 = __builtin_exp2f(fmaf(-(float)(d0 + 2), C, -L2PI));
    const float w3 = __builtin_exp2f(fmaf(-(float)(d0 + 3), C, -L2PI));

    float4 v = ((const float4*)x)[idx];
    v.x += __builtin_amdgcn_sinf(pe_rev(pos, w0));   // even d -> sin
    v.y += __builtin_amdgcn_cosf(pe_rev(pos, w1));   // odd d  -> cos
    v.z += __builtin_amdgcn_sinf(pe_rev(pos, w2));
    v.w += __builtin_amdgcn_cosf(pe_rev(pos, w3));
    ((float4*)out)[idx] = v;
}

extern "C" void kernel_launch(void* const* d_in, const int* in_sizes, int n_in,
                              void* d_out, int out_size, void* d_ws, size_t ws_size,
                              hipStream_t stream) {
    const float* x = (const float*)d_in[0];
    float* out     = (float*)d_out;
    pe_add_fused_kernel<<<TOTAL4 / 256, 256, 0, stream>>>(x, out);
}